// Round 1
// baseline (1235.405 us; speedup 1.0000x reference)
//
#include <hip/hip_runtime.h>
#include <cmath>

#define NB 16
#define MM 4096
#define MP1 4097
#define DD 512
#define LSEQ 196

__device__ __forceinline__ float sigf(float v) { return 1.0f / (1.0f + expf(-v)); }

// K1: per-row logits (fused GEMM x2 + tanh*sigmoid*Ww reduce) + partial z accumulation.
// Block = 256 thr (4 waves); 16 rows staged in LDS; wave handles 4 rows; lane handles
// 8 contiguous cols (float4-vectorized W loads, 16B/lane).
__global__ __launch_bounds__(256) void k_scores(
    const float* __restrict__ x, const float* __restrict__ feat_mem,
    const float* __restrict__ Wv, const float* __restrict__ bv,
    const float* __restrict__ Wu, const float* __restrict__ bu,
    const float* __restrict__ Ww, const float* __restrict__ bw,
    float* __restrict__ scores, float* __restrict__ zacc)
{
  const int b = blockIdx.y;
  const int row0 = blockIdx.x * 16;
  const int tid = threadIdx.x;
  const int wave = tid >> 6, lane = tid & 63;

  __shared__ __align__(16) float sfeat[16][DD];   // 32 KB
  __shared__ float sscore[16];

  // stage 16 rows of feat (mem rows, row 4096 = cls = x[b,0,:])
  for (int t = tid; t < 16 * (DD / 4); t += 256) {
    const int r = t >> 7;          // 128 float4 per row
    const int c4 = t & 127;
    const int row = row0 + r;
    float4 val = make_float4(0.f, 0.f, 0.f, 0.f);
    if (row < MP1) {
      const float* src = (row < MM) ? (feat_mem + ((size_t)b * MM + row) * DD)
                                    : (x + (size_t)b * LSEQ * DD);
      val = reinterpret_cast<const float4*>(src)[c4];
    }
    reinterpret_cast<float4*>(sfeat)[t] = val;
  }
  __syncthreads();

  const int r0 = wave * 4;
  float accv[4][8] = {};
  float accu[4][8] = {};
  const float* wvp = Wv + lane * 8;
  const float* wup = Wu + lane * 8;
  for (int k = 0; k < DD; ++k) {
    const float a0 = sfeat[r0 + 0][k];
    const float a1 = sfeat[r0 + 1][k];
    const float a2 = sfeat[r0 + 2][k];
    const float a3 = sfeat[r0 + 3][k];
    const float4 wv0 = *reinterpret_cast<const float4*>(wvp + (size_t)k * DD);
    const float4 wv1 = *reinterpret_cast<const float4*>(wvp + (size_t)k * DD + 4);
    const float4 wu0 = *reinterpret_cast<const float4*>(wup + (size_t)k * DD);
    const float4 wu1 = *reinterpret_cast<const float4*>(wup + (size_t)k * DD + 4);
    const float wv[8] = {wv0.x, wv0.y, wv0.z, wv0.w, wv1.x, wv1.y, wv1.z, wv1.w};
    const float wu[8] = {wu0.x, wu0.y, wu0.z, wu0.w, wu1.x, wu1.y, wu1.z, wu1.w};
#pragma unroll
    for (int c = 0; c < 8; ++c) {
      accv[0][c] = fmaf(a0, wv[c], accv[0][c]);
      accv[1][c] = fmaf(a1, wv[c], accv[1][c]);
      accv[2][c] = fmaf(a2, wv[c], accv[2][c]);
      accv[3][c] = fmaf(a3, wv[c], accv[3][c]);
      accu[0][c] = fmaf(a0, wu[c], accu[0][c]);
      accu[1][c] = fmaf(a1, wu[c], accu[1][c]);
      accu[2][c] = fmaf(a2, wu[c], accu[2][c]);
      accu[3][c] = fmaf(a3, wu[c], accu[3][c]);
    }
  }

  // epilogue: tanh(v+bv)*sigmoid(u+bu)*Ww  -> per-row partial, wave-reduce
  float part[4] = {0.f, 0.f, 0.f, 0.f};
#pragma unroll
  for (int c = 0; c < 8; ++c) {
    const int j = lane * 8 + c;
    const float bvj = bv[j], buj = bu[j], wwj = Ww[j];
#pragma unroll
    for (int r = 0; r < 4; ++r) {
      const float vv = tanhf(accv[r][c] + bvj);
      const float uu = sigf(accu[r][c] + buj);
      part[r] = fmaf(vv * uu, wwj, part[r]);
    }
  }
#pragma unroll
  for (int off = 32; off >= 1; off >>= 1) {
#pragma unroll
    for (int r = 0; r < 4; ++r) part[r] += __shfl_xor(part[r], off, 64);
  }
  if (lane == 0) {
    const float bw0 = bw[0];
#pragma unroll
    for (int r = 0; r < 4; ++r) {
      const int row = row0 + r0 + r;
      if (row < MP1) {
        const float sc = sigf(part[r] + bw0);
        scores[(size_t)b * MP1 + row] = sc;
        sscore[r0 + r] = sc;
      }
    }
  }
  __syncthreads();

  // partial z: block-local sum over its 16 rows, one atomic per d
  for (int d = tid; d < DD; d += 256) {
    float s = 0.f;
#pragma unroll
    for (int r = 0; r < 16; ++r) {
      if (row0 + r < MP1) s = fmaf(sscore[r], sfeat[r][d], s);
    }
    atomicAdd(&zacc[(size_t)b * DD + d], s);
  }
}

// K2: per-batch (16 blocks): argmin(score) ties->first; exact-rational argmax of
// mn/freq with mask; write z, freq_out, min_out; store rm/attn idx for gather.
__global__ __launch_bounds__(256) void k_finalize(
    const float* __restrict__ scores, const int* __restrict__ freq_mem,
    const int* __restrict__ min_mem, const float* __restrict__ zacc,
    float* __restrict__ out_z, float* __restrict__ out_freq,
    float* __restrict__ out_min, int* __restrict__ rm_attn)
{
  const int b = blockIdx.x;
  const int tid = threadIdx.x;
  __shared__ float sv[256];
  __shared__ int si[256];
  __shared__ int sn[256], sd[256], sj[256];
  __shared__ int s_attn, s_rm;

  // ---- argmin of scores (first occurrence) ----
  float bmin = INFINITY;
  int bidx = MP1;
  for (int i = tid; i < MP1; i += 256) {
    const float v = scores[(size_t)b * MP1 + i];
    if (v < bmin) { bmin = v; bidx = i; }   // i increasing -> first kept
  }
  sv[tid] = bmin; si[tid] = bidx;
  __syncthreads();
  for (int s = 128; s >= 1; s >>= 1) {
    if (tid < s) {
      const float v2 = sv[tid + s]; const int i2 = si[tid + s];
      if (v2 < sv[tid] || (v2 == sv[tid] && i2 < si[tid])) { sv[tid] = v2; si[tid] = i2; }
    }
    __syncthreads();
  }
  if (tid == 0) s_attn = si[0];
  __syncthreads();
  const int attn = s_attn;

  // ---- argmax of ratio = mn/freq * (freq>5), exact rational compare ----
  int bn = -1, bd = 1, bj = 0;
  for (int i = tid; i < MP1; i += 256) {
    int num, den;
    if (i < MM) {
      den = freq_mem[(size_t)b * MM + i] + 1;
      num = min_mem[(size_t)b * MM + i] + (i == attn ? 1 : 0);
      if (den <= 5) num = 0;
    } else { den = 1; num = 0; }   // cls: freq=1 -> masked
    if (num * bd > bn * den) { bn = num; bd = den; bj = i; }
  }
  sn[tid] = bn; sd[tid] = bd; sj[tid] = bj;
  __syncthreads();
  for (int s = 128; s >= 1; s >>= 1) {
    if (tid < s) {
      const int n2 = sn[tid + s], d2 = sd[tid + s], j2 = sj[tid + s];
      const int l = n2 * sd[tid], r = sn[tid] * d2;
      if (l > r || (l == r && j2 < sj[tid])) { sn[tid] = n2; sd[tid] = d2; sj[tid] = j2; }
    }
    __syncthreads();
  }
  if (tid == 0) { s_rm = sj[0]; rm_attn[b * 2] = attn; rm_attn[b * 2 + 1] = sj[0]; }
  __syncthreads();
  const int rm = s_rm;

  // ---- freq_out / min_out (skip rm row; row 4096 = cls: freq=1, mn=0(+attn hit)) ----
  for (int i = tid; i < MM; i += 256) {
    const int src = (i < rm) ? i : i + 1;
    int fv, mv;
    if (src < MM) {
      fv = freq_mem[(size_t)b * MM + src] + 1;
      mv = min_mem[(size_t)b * MM + src] + (src == attn ? 1 : 0);
    } else {
      fv = 1; mv = (attn == MM) ? 1 : 0;
    }
    out_freq[(size_t)b * MM + i] = (float)fv;
    out_min[(size_t)b * MM + i] = (float)mv;
  }
  for (int d = tid; d < DD; d += 256) out_z[(size_t)b * DD + d] = zacc[(size_t)b * DD + d];
}

// K3: feat_out gather (skip rm row), pure float4 copy. 4 rows/block, 64 lanes/row.
__global__ __launch_bounds__(256) void k_gather(
    const float* __restrict__ feat_mem, const float* __restrict__ x,
    const int* __restrict__ rm_attn, float* __restrict__ out_feat)
{
  const int b = blockIdx.y;
  const int rm = rm_attn[b * 2 + 1];
  const int row = blockIdx.x * 4 + (threadIdx.x >> 6);
  const int lane = threadIdx.x & 63;
  const int src = (row < rm) ? row : row + 1;
  const float* sp = (src < MM) ? (feat_mem + ((size_t)b * MM + src) * DD)
                               : (x + (size_t)b * LSEQ * DD);
  float* dp = out_feat + ((size_t)b * MM + row) * DD;
  const float4 v0 = reinterpret_cast<const float4*>(sp)[lane];
  const float4 v1 = reinterpret_cast<const float4*>(sp)[lane + 64];
  reinterpret_cast<float4*>(dp)[lane] = v0;
  reinterpret_cast<float4*>(dp)[lane + 64] = v1;
}

extern "C" void kernel_launch(void* const* d_in, const int* in_sizes, int n_in,
                              void* d_out, int out_size, void* d_ws, size_t ws_size,
                              hipStream_t stream) {
  const float* x        = (const float*)d_in[0];
  const float* feat_mem = (const float*)d_in[1];
  const int*   freq_mem = (const int*)d_in[2];
  const int*   min_mem  = (const int*)d_in[3];
  const float* Wv       = (const float*)d_in[4];
  const float* bv       = (const float*)d_in[5];
  const float* Wu       = (const float*)d_in[6];
  const float* bu       = (const float*)d_in[7];
  const float* Ww       = (const float*)d_in[8];
  const float* bw       = (const float*)d_in[9];

  float* ws     = (float*)d_ws;
  float* scores = ws;                       // NB*MP1
  float* zacc   = ws + NB * MP1;            // NB*DD
  int*   rm_attn = (int*)(ws + NB * MP1 + NB * DD);  // 2*NB ints

  float* out_z    = (float*)d_out;                    // NB*DD
  float* out_feat = out_z + NB * DD;                  // NB*MM*DD
  float* out_freq = out_feat + (size_t)NB * MM * DD;  // NB*MM
  float* out_min  = out_freq + (size_t)NB * MM;       // NB*MM

  hipMemsetAsync(zacc, 0, NB * DD * sizeof(float), stream);

  dim3 g1((MP1 + 15) / 16, NB);
  k_scores<<<g1, dim3(256), 0, stream>>>(x, feat_mem, Wv, bv, Wu, bu, Ww, bw, scores, zacc);
  k_finalize<<<dim3(NB), dim3(256), 0, stream>>>(scores, freq_mem, min_mem, zacc,
                                                 out_z, out_freq, out_min, rm_attn);
  k_gather<<<dim3(MM / 4, NB), dim3(256), 0, stream>>>(feat_mem, x, rm_attn, out_feat);
}

// Round 2
// 364.510 us; speedup vs baseline: 3.3892x; 3.3892x over previous
//
#include <hip/hip_runtime.h>
#include <cmath>

#define NB 16
#define MM 4096
#define MP1 4097
#define DD 512
#define LSEQ 196
#define BM 64
#define KC 128
#define NKC (DD / KC)
#define NRB ((MP1 + BM - 1) / BM)   // 65
#define PS (32 * 16 * 512)          // plane stride in ushorts (1 plane = 512x512 bf16)

typedef float f32x4 __attribute__((ext_vector_type(4)));
typedef short bf16x8 __attribute__((ext_vector_type(8)));
typedef unsigned short u16x8 __attribute__((ext_vector_type(8)));

__device__ __forceinline__ unsigned short bf16_rne(float x) {
  union { float f; unsigned u; } c; c.f = x;
  unsigned u = c.u;
  u += 0x7fffu + ((u >> 16) & 1u);
  return (unsigned short)(u >> 16);
}
__device__ __forceinline__ float bf16_to_f(unsigned short h) {
  union { unsigned u; float f; } c; c.u = ((unsigned)h) << 16;
  return c.f;
}
__device__ __forceinline__ float sigf(float v) { return 1.0f / (1.0f + expf(-v)); }

// ---- pack Wv,Wu into MFMA-frag-ordered hi/lo bf16 planes -------------------
// plane p: 0=Wv_hi 1=Wv_lo 2=Wu_hi 3=Wu_lo
// frag addr (ushorts): ((p*32 + ctg)*16 + ksg)*512 + lane*8
// element: W[k][col], col = ctg*16 + (lane&15), k = ksg*32 + (lane>>4)*8 + i
__global__ __launch_bounds__(256) void k_packW(const float* __restrict__ Wv,
                                               const float* __restrict__ Wu,
                                               unsigned short* __restrict__ Bp) {
  const int gid = blockIdx.x * 256 + threadIdx.x;  // 65536 total
  const int l = gid & 63;
  const int ksg = (gid >> 6) & 15;
  const int ctg = (gid >> 10) & 31;
  const int mat = gid >> 15;
  const float* W = mat ? Wu : Wv;
  const int col = ctg * 16 + (l & 15);
  const int kb = ksg * 32 + (l >> 4) * 8;
  u16x8 hi, lo;
#pragma unroll
  for (int i = 0; i < 8; ++i) {
    const float w = W[(size_t)(kb + i) * DD + col];
    const unsigned short h = bf16_rne(w);
    hi[i] = h;
    lo[i] = bf16_rne(w - bf16_to_f(h));
  }
  const size_t fo = ((size_t)(ctg * 16 + ksg)) * 512 + l * 8;
  *(u16x8*)(Bp + (size_t)(mat * 2 + 0) * PS + fo) = hi;
  *(u16x8*)(Bp + (size_t)(mat * 2 + 1) * PS + fo) = lo;
}

// ---- fused 2xGEMM + gated score, split-bf16 MFMA ---------------------------
__global__ __launch_bounds__(512) void k_scores(
    const float* __restrict__ x, const float* __restrict__ feat_mem,
    const unsigned short* __restrict__ Bp,
    const float* __restrict__ bv, const float* __restrict__ bu,
    const float* __restrict__ Ww, const float* __restrict__ bw,
    float* __restrict__ scores) {
  const int b = blockIdx.y;
  const int rb = blockIdx.x;
  const int row0 = rb * BM;
  const int tid = threadIdx.x;
  const int wave = tid >> 6, l = tid & 63;

  __shared__ unsigned short lds[2 * 64 * 128];  // hi plane [0..8191], lo plane [8192..]
  __shared__ float sred[8][64];

  f32x4 accv[4][4], accu[4][4];
#pragma unroll
  for (int i = 0; i < 4; ++i)
#pragma unroll
    for (int j = 0; j < 4; ++j) {
      accv[i][j] = (f32x4){0.f, 0.f, 0.f, 0.f};
      accu[i][j] = (f32x4){0.f, 0.f, 0.f, 0.f};
    }

  // staging mapping: thread -> (row, 16-k group)
  const int srow = tid >> 3;
  const int skg = tid & 7;
  const int grow = row0 + srow;
  const float* srcrow = nullptr;
  if (grow < MM) srcrow = feat_mem + ((size_t)b * MM + grow) * DD;
  else if (grow == MM) srcrow = x + (size_t)b * LSEQ * DD;
  const int sbase = srow * 128 + ((skg * 16) ^ ((srow & 7) << 4));

  for (int kc = 0; kc < NKC; ++kc) {
    // ---- stage: fp32 -> (hi,lo) bf16, XOR-swizzled LDS ----
    {
      float v[16];
#pragma unroll
      for (int q = 0; q < 4; ++q) {
        float4 t = srcrow ? ((const float4*)(srcrow + kc * KC + skg * 16))[q]
                          : make_float4(0.f, 0.f, 0.f, 0.f);
        v[q * 4 + 0] = t.x; v[q * 4 + 1] = t.y; v[q * 4 + 2] = t.z; v[q * 4 + 3] = t.w;
      }
      u16x8 h0, h1, l0, l1;
#pragma unroll
      for (int i = 0; i < 8; ++i) {
        unsigned short h = bf16_rne(v[i]);
        h0[i] = h; l0[i] = bf16_rne(v[i] - bf16_to_f(h));
        h = bf16_rne(v[8 + i]);
        h1[i] = h; l1[i] = bf16_rne(v[8 + i] - bf16_to_f(h));
      }
      *(u16x8*)(lds + sbase) = h0;
      *(u16x8*)(lds + sbase + 8) = h1;
      *(u16x8*)(lds + 8192 + sbase) = l0;
      *(u16x8*)(lds + 8192 + sbase + 8) = l1;
    }
    __syncthreads();

    for (int ks = 0; ks < 4; ++ks) {
      bf16x8 hiA[4], loA[4];
#pragma unroll
      for (int rt = 0; rt < 4; ++rt) {
        const int row = rt * 16 + (l & 15);
        const int kidx = (ks * 32 + (l >> 4) * 8) ^ ((row & 7) << 4);
        hiA[rt] = *(const bf16x8*)(lds + row * 128 + kidx);
        loA[rt] = *(const bf16x8*)(lds + 8192 + row * 128 + kidx);
      }
      const int ksg = kc * 4 + ks;
#pragma unroll
      for (int ct = 0; ct < 4; ++ct) {
        const int ctg = wave * 4 + ct;
        const unsigned short* fb = Bp + ((size_t)(ctg * 16 + ksg)) * 512 + l * 8;
        const bf16x8 hv = *(const bf16x8*)(fb);
        const bf16x8 lv = *(const bf16x8*)(fb + PS);
        const bf16x8 hu = *(const bf16x8*)(fb + 2 * PS);
        const bf16x8 lu = *(const bf16x8*)(fb + 3 * PS);
#pragma unroll
        for (int rt = 0; rt < 4; ++rt) {
          accv[rt][ct] = __builtin_amdgcn_mfma_f32_16x16x32_bf16(hiA[rt], hv, accv[rt][ct], 0, 0, 0);
          accv[rt][ct] = __builtin_amdgcn_mfma_f32_16x16x32_bf16(hiA[rt], lv, accv[rt][ct], 0, 0, 0);
          accv[rt][ct] = __builtin_amdgcn_mfma_f32_16x16x32_bf16(loA[rt], hv, accv[rt][ct], 0, 0, 0);
          accu[rt][ct] = __builtin_amdgcn_mfma_f32_16x16x32_bf16(hiA[rt], hu, accu[rt][ct], 0, 0, 0);
          accu[rt][ct] = __builtin_amdgcn_mfma_f32_16x16x32_bf16(hiA[rt], lu, accu[rt][ct], 0, 0, 0);
          accu[rt][ct] = __builtin_amdgcn_mfma_f32_16x16x32_bf16(loA[rt], hu, accu[rt][ct], 0, 0, 0);
        }
      }
    }
    __syncthreads();
  }

  // ---- epilogue: tanh(v+bv)*sig(u+bu)*Ww, reduce over cols ----
  float prow[4][4];
#pragma unroll
  for (int i = 0; i < 4; ++i)
#pragma unroll
    for (int j = 0; j < 4; ++j) prow[i][j] = 0.f;

#pragma unroll
  for (int ct = 0; ct < 4; ++ct) {
    const int col = wave * 64 + ct * 16 + (l & 15);
    const float bvc = bv[col], buc = bu[col], wwc = Ww[col];
#pragma unroll
    for (int rt = 0; rt < 4; ++rt)
#pragma unroll
      for (int r = 0; r < 4; ++r) {
        const float vv = tanhf(accv[rt][ct][r] + bvc);
        const float uu = sigf(accu[rt][ct][r] + buc);
        prow[rt][r] = fmaf(vv * uu, wwc, prow[rt][r]);
      }
  }
#pragma unroll
  for (int off = 1; off < 16; off <<= 1)
#pragma unroll
    for (int rt = 0; rt < 4; ++rt)
#pragma unroll
      for (int r = 0; r < 4; ++r) prow[rt][r] += __shfl_xor(prow[rt][r], off, 64);

  if ((l & 15) == 0) {
#pragma unroll
    for (int rt = 0; rt < 4; ++rt)
#pragma unroll
      for (int r = 0; r < 4; ++r) sred[wave][rt * 16 + (l >> 4) * 4 + r] = prow[rt][r];
  }
  __syncthreads();
  if (tid < 64) {
    float s = bw[0];
#pragma unroll
    for (int w = 0; w < 8; ++w) s += sred[w][tid];
    const int grow2 = row0 + tid;
    if (grow2 < MP1) scores[(size_t)b * MP1 + grow2] = sigf(s);
  }
}

// ---- z = sum_rows score*feat (streaming, one pass over feat) ---------------
__global__ __launch_bounds__(256) void k_z(const float* __restrict__ x,
                                           const float* __restrict__ feat_mem,
                                           const float* __restrict__ scores,
                                           float* __restrict__ zacc) {
  const int b = blockIdx.y;
  const int rc = blockIdx.x >> 2;
  const int dc = blockIdx.x & 3;
  const int t = threadIdx.x;
  const int rpar = t >> 5;
  const int d = dc * 128 + (t & 31) * 4;
  const int rbeg = rc * 512;
  const int rend = (rc == 7) ? MP1 : rc * 512 + 512;
  float4 acc = make_float4(0.f, 0.f, 0.f, 0.f);
  for (int r = rbeg + rpar; r < rend; r += 8) {
    const float s = scores[(size_t)b * MP1 + r];
    const float* src = (r < MM) ? feat_mem + ((size_t)b * MM + r) * DD
                                : x + (size_t)b * LSEQ * DD;
    const float4 f = *(const float4*)(src + d);
    acc.x = fmaf(s, f.x, acc.x);
    acc.y = fmaf(s, f.y, acc.y);
    acc.z = fmaf(s, f.z, acc.z);
    acc.w = fmaf(s, f.w, acc.w);
  }
  __shared__ float4 red[256];
  red[t] = acc;
  __syncthreads();
  if (t < 32) {
    float4 s = red[t];
#pragma unroll
    for (int j = 1; j < 8; ++j) {
      const float4 o = red[t + 32 * j];
      s.x += o.x; s.y += o.y; s.z += o.z; s.w += o.w;
    }
    atomicAdd(&zacc[(size_t)b * DD + d + 0], s.x);
    atomicAdd(&zacc[(size_t)b * DD + d + 1], s.y);
    atomicAdd(&zacc[(size_t)b * DD + d + 2], s.z);
    atomicAdd(&zacc[(size_t)b * DD + d + 3], s.w);
  }
}

// ---- argmin/argmax + freq/min outputs (verified R1) ------------------------
__global__ __launch_bounds__(256) void k_finalize(
    const float* __restrict__ scores, const int* __restrict__ freq_mem,
    const int* __restrict__ min_mem, const float* __restrict__ zacc,
    float* __restrict__ out_z, float* __restrict__ out_freq,
    float* __restrict__ out_min, int* __restrict__ rm_attn) {
  const int b = blockIdx.x;
  const int tid = threadIdx.x;
  __shared__ float sv[256];
  __shared__ int si[256];
  __shared__ int sn[256], sd[256], sj[256];
  __shared__ int s_attn, s_rm;

  float bmin = INFINITY;
  int bidx = MP1;
  for (int i = tid; i < MP1; i += 256) {
    const float v = scores[(size_t)b * MP1 + i];
    if (v < bmin) { bmin = v; bidx = i; }
  }
  sv[tid] = bmin; si[tid] = bidx;
  __syncthreads();
  for (int s = 128; s >= 1; s >>= 1) {
    if (tid < s) {
      const float v2 = sv[tid + s]; const int i2 = si[tid + s];
      if (v2 < sv[tid] || (v2 == sv[tid] && i2 < si[tid])) { sv[tid] = v2; si[tid] = i2; }
    }
    __syncthreads();
  }
  if (tid == 0) s_attn = si[0];
  __syncthreads();
  const int attn = s_attn;

  int bn = -1, bd = 1, bj = 0;
  for (int i = tid; i < MP1; i += 256) {
    int num, den;
    if (i < MM) {
      den = freq_mem[(size_t)b * MM + i] + 1;
      num = min_mem[(size_t)b * MM + i] + (i == attn ? 1 : 0);
      if (den <= 5) num = 0;
    } else { den = 1; num = 0; }
    if (num * bd > bn * den) { bn = num; bd = den; bj = i; }
  }
  sn[tid] = bn; sd[tid] = bd; sj[tid] = bj;
  __syncthreads();
  for (int s = 128; s >= 1; s >>= 1) {
    if (tid < s) {
      const int n2 = sn[tid + s], d2 = sd[tid + s], j2 = sj[tid + s];
      const int lft = n2 * sd[tid], rgt = sn[tid] * d2;
      if (lft > rgt || (lft == rgt && j2 < sj[tid])) { sn[tid] = n2; sd[tid] = d2; sj[tid] = j2; }
    }
    __syncthreads();
  }
  if (tid == 0) { s_rm = sj[0]; rm_attn[b * 2] = attn; rm_attn[b * 2 + 1] = sj[0]; }
  __syncthreads();
  const int rm = s_rm;

  for (int i = tid; i < MM; i += 256) {
    const int src = (i < rm) ? i : i + 1;
    int fv, mv;
    if (src < MM) {
      fv = freq_mem[(size_t)b * MM + src] + 1;
      mv = min_mem[(size_t)b * MM + src] + (src == attn ? 1 : 0);
    } else {
      fv = 1; mv = (attn == MM) ? 1 : 0;
    }
    out_freq[(size_t)b * MM + i] = (float)fv;
    out_min[(size_t)b * MM + i] = (float)mv;
  }
  for (int d = tid; d < DD; d += 256) out_z[(size_t)b * DD + d] = zacc[(size_t)b * DD + d];
}

// ---- feat_out gather (verified R1) ------------------------------------------
__global__ __launch_bounds__(256) void k_gather(
    const float* __restrict__ feat_mem, const float* __restrict__ x,
    const int* __restrict__ rm_attn, float* __restrict__ out_feat) {
  const int b = blockIdx.y;
  const int rm = rm_attn[b * 2 + 1];
  const int row = blockIdx.x * 4 + (threadIdx.x >> 6);
  const int lane = threadIdx.x & 63;
  const int src = (row < rm) ? row : row + 1;
  const float* sp = (src < MM) ? (feat_mem + ((size_t)b * MM + src) * DD)
                               : (x + (size_t)b * LSEQ * DD);
  float* dp = out_feat + ((size_t)b * MM + row) * DD;
  const float4 v0 = reinterpret_cast<const float4*>(sp)[lane];
  const float4 v1 = reinterpret_cast<const float4*>(sp)[lane + 64];
  reinterpret_cast<float4*>(dp)[lane] = v0;
  reinterpret_cast<float4*>(dp)[lane + 64] = v1;
}

extern "C" void kernel_launch(void* const* d_in, const int* in_sizes, int n_in,
                              void* d_out, int out_size, void* d_ws, size_t ws_size,
                              hipStream_t stream) {
  const float* x        = (const float*)d_in[0];
  const float* feat_mem = (const float*)d_in[1];
  const int*   freq_mem = (const int*)d_in[2];
  const int*   min_mem  = (const int*)d_in[3];
  const float* Wv       = (const float*)d_in[4];
  const float* bv       = (const float*)d_in[5];
  const float* Wu       = (const float*)d_in[6];
  const float* bu       = (const float*)d_in[7];
  const float* Ww       = (const float*)d_in[8];
  const float* bw       = (const float*)d_in[9];

  float* ws = (float*)d_ws;
  float* scores = ws;                              // 65552 floats
  float* zacc = ws + NB * MP1;                     // 8192 floats
  int* rm_attn = (int*)(ws + NB * MP1 + NB * DD);  // 32 ints
  unsigned short* Bp = (unsigned short*)(ws + NB * MP1 + NB * DD + 32);  // 2 MB

  float* out_z    = (float*)d_out;
  float* out_feat = out_z + NB * DD;
  float* out_freq = out_feat + (size_t)NB * MM * DD;
  float* out_min  = out_freq + (size_t)NB * MM;

  hipMemsetAsync(zacc, 0, NB * DD * sizeof(float), stream);

  k_packW<<<dim3(256), dim3(256), 0, stream>>>(Wv, Wu, Bp);
  k_scores<<<dim3(NRB, NB), dim3(512), 0, stream>>>(x, feat_mem, Bp, bv, bu, Ww, bw, scores);
  k_z<<<dim3(32, NB), dim3(256), 0, stream>>>(x, feat_mem, scores, zacc);
  k_finalize<<<dim3(NB), dim3(256), 0, stream>>>(scores, freq_mem, min_mem, zacc,
                                                 out_z, out_freq, out_min, rm_attn);
  k_gather<<<dim3(MM / 4, NB), dim3(256), 0, stream>>>(feat_mem, x, rm_attn, out_feat);
}